// Round 1
// baseline (382.838 us; speedup 1.0000x reference)
//
#include <hip/hip_runtime.h>
#include <math.h>

// Problem constants (from reference): B=256, N=512, M=1024
#define BB 256
#define NN 512
#define MM 1024
#define TOTAL (BB * MM)   // 262144 claims
#define EPS_P 1e-7f

// ws layout (16 bytes, zeroed via hipMemsetAsync each call):
//   [0] float  loss_sum
//   [1] int    valid_count
//   [2] int    mask_is_bytes flag (1 = 1-byte bool storage, 0 = int32 storage)

// --- mask storage detection -------------------------------------------------
// If claim_mask was widened to int32 (values 0/1), every byte at a
// non-4-aligned offset is zero. If it's native 1-byte bools, ~half of those
// 768 positions in the first 1 KiB are nonzero. Single thread, reads only the
// first 1024 bytes (safe under either storage: buffer is >=256 KiB).
__global__ void detect_mask_kernel(const unsigned char* __restrict__ mask_raw,
                                   int* __restrict__ flag) {
    int f = 0;
    for (int i = 0; i < 1024; ++i) {
        if ((i & 3) != 0 && mask_raw[i] != 0) { f = 1; break; }
    }
    *flag = f;
}

// --- main reduction ---------------------------------------------------------
__global__ __launch_bounds__(256)
void claim_loss_kernel(const float* __restrict__ adj,
                       const int*   __restrict__ var_a,
                       const int*   __restrict__ var_b,
                       const int*   __restrict__ rel,
                       const int*   __restrict__ is_true,
                       const void*  __restrict__ mask,
                       const int*   __restrict__ mask_flag,
                       float* __restrict__ loss_sum,
                       int*   __restrict__ valid_cnt) {
    const int j = blockIdx.x * blockDim.x + threadIdx.x;
    const int bytes_mode = *mask_flag;   // uniform; L1-cached broadcast

    float loss  = 0.0f;
    int   valid = 0;
    if (j < TOTAL) {
        int m = bytes_mode ? (int)((const unsigned char*)mask)[j]
                           : ((const int*)mask)[j];
        if (m == 0) {                      // True = padding; valid when 0
            const int b = j >> 10;         // M = 1024
            const int a = var_a[j];
            const int c = var_b[j];
            const int r = rel[j];
            const int t = is_true[j];
            float p = adj[(size_t)b * (NN * NN) + a * NN + c];
            // 0=CAUSES,1=FORBIDS,2=ANCESTOR,3=NON_ANCESTOR, >=4 -> 0.5
            float prob = (r == 1 || r == 3) ? (1.0f - p) : p;
            if (r >= 4) prob = 0.5f;
            prob = fminf(fmaxf(prob, EPS_P), 1.0f - EPS_P);
            loss = t ? -logf(prob) : -log1pf(-prob);
            valid = 1;
        }
    }

    // wave-64 butterfly reduce
    #pragma unroll
    for (int off = 32; off > 0; off >>= 1) {
        loss  += __shfl_down(loss, off, 64);
        valid += __shfl_down(valid, off, 64);
    }

    __shared__ float s_l[4];
    __shared__ int   s_v[4];
    const int lane = threadIdx.x & 63;
    const int wave = threadIdx.x >> 6;
    if (lane == 0) { s_l[wave] = loss; s_v[wave] = valid; }
    __syncthreads();
    if (threadIdx.x == 0) {
        float L = s_l[0] + s_l[1] + s_l[2] + s_l[3];
        int   V = s_v[0] + s_v[1] + s_v[2] + s_v[3];
        atomicAdd(loss_sum, L);
        atomicAdd(valid_cnt, V);
    }
}

// --- finalize ---------------------------------------------------------------
__global__ void finalize_kernel(const float* __restrict__ loss_sum,
                                const int*   __restrict__ valid_cnt,
                                float* __restrict__ out) {
    float n = (float)(*valid_cnt);
    out[0] = (n > 0.0f) ? (*loss_sum / fmaxf(n, 1.0f)) : 0.0f;
}

extern "C" void kernel_launch(void* const* d_in, const int* in_sizes, int n_in,
                              void* d_out, int out_size, void* d_ws, size_t ws_size,
                              hipStream_t stream) {
    const float* adj     = (const float*)d_in[0];
    const int*   var_a   = (const int*)d_in[1];
    const int*   var_b   = (const int*)d_in[2];
    const int*   rel     = (const int*)d_in[3];
    const int*   is_true = (const int*)d_in[4];
    const void*  mask    = d_in[5];

    float* ws_sum  = (float*)d_ws;
    int*   ws_cnt  = (int*)d_ws + 1;
    int*   ws_flag = (int*)d_ws + 2;
    float* out     = (float*)d_out;

    hipMemsetAsync(d_ws, 0, 16, stream);
    detect_mask_kernel<<<1, 1, 0, stream>>>((const unsigned char*)mask, ws_flag);
    claim_loss_kernel<<<TOTAL / 256, 256, 0, stream>>>(
        adj, var_a, var_b, rel, is_true, mask, ws_flag, ws_sum, ws_cnt);
    finalize_kernel<<<1, 1, 0, stream>>>(ws_sum, ws_cnt, out);
}

// Round 2
// 309.091 us; speedup vs baseline: 1.2386x; 1.2386x over previous
//
#include <hip/hip_runtime.h>
#include <math.h>

// Problem constants (from reference): B=256, N=512, M=1024
#define BB 256
#define NN 512
#define MM 1024
#define TOTAL (BB * MM)   // 262144 claims
#define NBLK (TOTAL / 256) // 1024 blocks, 1 claim/thread
#define EPS_P 1e-7f

// ws layout: float part_sum[NBLK]; float part_cnt[NBLK]
// (fully overwritten every call — no init needed)

__global__ __launch_bounds__(256)
void claim_loss_main(const float* __restrict__ adj,
                     const int*   __restrict__ var_a,
                     const int*   __restrict__ var_b,
                     const int*   __restrict__ rel,
                     const int*   __restrict__ is_true,
                     const unsigned int* __restrict__ mask_raw,
                     float* __restrict__ part_sum,
                     float* __restrict__ part_cnt) {
    // --- inline mask-storage detection ---------------------------------
    // All waves in all blocks inspect the SAME first 64 words of the mask
    // buffer (1 broadcast-cached load/thread). int32 0/1 storage -> upper
    // 3 bytes of every word are zero. byte-bool storage -> some upper byte
    // nonzero w.p. 1 - 8^-64. Identical data => identical flag everywhere.
    const unsigned int w = mask_raw[threadIdx.x & 63];
    const bool bytes_mode = (__ballot((w & 0xFFFFFF00u) != 0u) != 0ull);

    const int j = blockIdx.x * 256 + threadIdx.x;

    const int m = bytes_mode ? (int)((const unsigned char*)mask_raw)[j]
                             : ((const int*)mask_raw)[j];

    float loss  = 0.0f;
    float valid = 0.0f;
    if (m == 0) {                       // True = padding; valid when 0
        const int b = j >> 10;          // M = 1024
        const int a = var_a[j];
        const int c = var_b[j];
        const int r = rel[j];
        const int t = is_true[j];
        float p = adj[((size_t)b << 18) + (a << 9) + c];  // N=512
        // 0=CAUSES,1=FORBIDS,2=ANCESTOR,3=NON_ANCESTOR, >=4 -> 0.5
        float prob = (r == 1 || r == 3) ? (1.0f - p) : p;
        if (r >= 4) prob = 0.5f;
        prob = fminf(fmaxf(prob, EPS_P), 1.0f - EPS_P);
        loss  = t ? -logf(prob) : -log1pf(-prob);
        valid = 1.0f;
    }

    // wave-64 reduce
    #pragma unroll
    for (int off = 32; off > 0; off >>= 1) {
        loss  += __shfl_down(loss, off, 64);
        valid += __shfl_down(valid, off, 64);
    }

    __shared__ float s_l[4];
    __shared__ float s_v[4];
    const int lane = threadIdx.x & 63;
    const int wave = threadIdx.x >> 6;
    if (lane == 0) { s_l[wave] = loss; s_v[wave] = valid; }
    __syncthreads();
    if (threadIdx.x == 0) {
        part_sum[blockIdx.x] = s_l[0] + s_l[1] + s_l[2] + s_l[3];
        part_cnt[blockIdx.x] = s_v[0] + s_v[1] + s_v[2] + s_v[3];
    }
}

__global__ __launch_bounds__(1024)
void claim_loss_final(const float* __restrict__ part_sum,
                      const float* __restrict__ part_cnt,
                      float* __restrict__ out) {
    float s = part_sum[threadIdx.x];
    float c = part_cnt[threadIdx.x];

    #pragma unroll
    for (int off = 32; off > 0; off >>= 1) {
        s += __shfl_down(s, off, 64);
        c += __shfl_down(c, off, 64);
    }

    __shared__ float s_l[16];
    __shared__ float s_v[16];
    const int lane = threadIdx.x & 63;
    const int wave = threadIdx.x >> 6;
    if (lane == 0) { s_l[wave] = s; s_v[wave] = c; }
    __syncthreads();

    if (threadIdx.x == 0) {
        float S = 0.0f, C = 0.0f;
        #pragma unroll
        for (int i = 0; i < 16; ++i) { S += s_l[i]; C += s_v[i]; }
        out[0] = (C > 0.0f) ? (S / fmaxf(C, 1.0f)) : 0.0f;
    }
}

extern "C" void kernel_launch(void* const* d_in, const int* in_sizes, int n_in,
                              void* d_out, int out_size, void* d_ws, size_t ws_size,
                              hipStream_t stream) {
    const float* adj     = (const float*)d_in[0];
    const int*   var_a   = (const int*)d_in[1];
    const int*   var_b   = (const int*)d_in[2];
    const int*   rel     = (const int*)d_in[3];
    const int*   is_true = (const int*)d_in[4];
    const unsigned int* mask = (const unsigned int*)d_in[5];

    float* part_sum = (float*)d_ws;
    float* part_cnt = (float*)d_ws + NBLK;
    float* out      = (float*)d_out;

    claim_loss_main<<<NBLK, 256, 0, stream>>>(
        adj, var_a, var_b, rel, is_true, mask, part_sum, part_cnt);
    claim_loss_final<<<1, 1024, 0, stream>>>(part_sum, part_cnt, out);
}